// Round 6
// baseline (144.871 us; speedup 1.0000x reference)
//
#include <hip/hip_runtime.h>
#include <hip/hip_bf16.h>

// SemanticDecoder: mean = b@Wmu+bmu; s = b@Wsig+bsig; var = s*s;
// sample = mean + |s|*eps.  B=65536, K=64, D=300. f32 in/out.
// Outputs concatenated: [sample, mean, var], each B*D.
//
// R6: K-split. Lane = (col, k-half): lanes 0-31 cols c with k 0..31,
// lanes 32-63 same cols k 32..63. Per-thread weights = 32 VGPRs (allocator
// cannot justify evicting), partial sums combined via __shfl_xor(32).
// 640-thread blocks (10 waves x 32 cols = 320 >= 300) -> ~3 blocks/CU
// = ~30 waves/CU of TLP. Stores: half-wave 128B contiguous chunks
// (lanes<32: sample+mean; lanes>=32: var) -> same ideal 237 MB WRITE_SIZE.

#define B_ROWS 65536
#define K_DIM 64
#define D_DIM 300
#define ROWS_PER_BLOCK 64
#define THREADS 640

typedef __fp16 half2v __attribute__((ext_vector_type(2)));
typedef __fp16 half4v __attribute__((ext_vector_type(4)));
typedef __fp16 half8v __attribute__((ext_vector_type(8)));

__device__ __forceinline__ float dot2h(half2v a, half2v b, float c) {
#if __has_builtin(__builtin_amdgcn_fdot2)
    return __builtin_amdgcn_fdot2(a, b, c, false);
#else
    return fmaf((float)a[0], (float)b[0], fmaf((float)a[1], (float)b[1], c));
#endif
}

// ---- kernel 1: W[64][300] f32 -> wp[m][d][k] f16 (transposed, packed) ----
__global__ void pack_wT_kernel(const float* __restrict__ Wmu,
                               const float* __restrict__ Wsig,
                               __fp16* __restrict__ wp)
{
    const int t = blockIdx.x * blockDim.x + threadIdx.x;
    if (t >= 2 * D_DIM * (K_DIM / 8)) return;   // 4800 units of 8 k-values
    const int g = t & 7;
    const int d = (t >> 3) % D_DIM;
    const int m = t / (D_DIM * 8);
    const float* W = m ? Wsig : Wmu;
    half8v o;
    #pragma unroll
    for (int e = 0; e < 8; ++e)
        o[e] = (__fp16)W[(size_t)(g * 8 + e) * D_DIM + d];
    *reinterpret_cast<half8v*>(&wp[((size_t)m * D_DIM + d) * K_DIM + g * 8]) = o;
}

// ---- main kernel ---------------------------------------------------------
__global__ __launch_bounds__(THREADS, 2) void sem_dec_kernel(
    const float* __restrict__ b,
    const float* __restrict__ bmu,
    const float* __restrict__ bsig,
    const float* __restrict__ eps,
    const __fp16* __restrict__ wp,
    float* __restrict__ out)
{
    __shared__ __fp16 lds_bh[ROWS_PER_BLOCK * K_DIM]; // 8 KB packed f16

    const int tid  = threadIdx.x;
    const int row0 = blockIdx.x * ROWS_PER_BLOCK;

    // ---- stage b[row0:row0+64, 0:64] -> LDS as f16, coalesced float4 in ----
    {
        const float4* gb = reinterpret_cast<const float4*>(b + (size_t)row0 * K_DIM);
        const int n4 = ROWS_PER_BLOCK * K_DIM / 4; // 1024
        for (int i = tid; i < n4; i += THREADS) {
            float4 v = gb[i];
            half2v p0 = __builtin_amdgcn_cvt_pkrtz(v.x, v.y);
            half2v p1 = __builtin_amdgcn_cvt_pkrtz(v.z, v.w);
            half4v p = __builtin_shufflevector(p0, p1, 0, 1, 2, 3);
            *reinterpret_cast<half4v*>(&lds_bh[4 * i]) = p; // ds_write_b64
        }
    }
    __syncthreads();

    const int lane  = tid & 63;
    const int wid   = tid >> 6;            // 0..9
    const int khalf = lane >> 5;           // 0: k 0..31, 1: k 32..63
    const int cr    = wid * 32 + (lane & 31);
    const bool cval = (cr < D_DIM);
    const int c     = cval ? cr : (D_DIM - 1);  // clamp for safe addressing
    const int k0    = khalf * 32;

    // ---- this thread's k-half weight slice: 4+4 half8v = 32 VGPRs ----
    half8v wmu_r[4], wsig_r[4];
    {
        const half8v* wm = reinterpret_cast<const half8v*>(
            wp + (size_t)c * K_DIM + k0);
        const half8v* ws = reinterpret_cast<const half8v*>(
            wp + ((size_t)D_DIM + c) * K_DIM + k0);
        #pragma unroll
        for (int j = 0; j < 4; ++j) { wmu_r[j] = wm[j]; wsig_r[j] = ws[j]; }
    }
    const float bm = bmu[c];
    const float bs = bsig[c];

    const size_t BD = (size_t)B_ROWS * D_DIM;
    size_t o = (size_t)row0 * D_DIM + c;   // row cursor (per-lane col)

    // eps software pipeline: 4-row lead (all lanes load; halves share 128B)
    float e0 = eps[o];
    float e1 = eps[o +     D_DIM];
    float e2 = eps[o + 2 * D_DIM];
    float e3 = eps[o + 3 * D_DIM];

    for (int rg = 0; rg < ROWS_PER_BLOCK; rg += 4) {
        const float f0 = e0, f1 = e1, f2 = e2, f3 = e3;
        if (rg + 4 < ROWS_PER_BLOCK) {
            const size_t p = o + 4 * (size_t)D_DIM;
            e0 = eps[p];
            e1 = eps[p +     D_DIM];
            e2 = eps[p + 2 * D_DIM];
            e3 = eps[p + 3 * D_DIM];
        }
        #pragma unroll
        for (int j = 0; j < 4; ++j) {
            const float e = (j == 0) ? f0 : (j == 1) ? f1 : (j == 2) ? f2 : f3;
            const half8v* bp = reinterpret_cast<const half8v*>(
                &lds_bh[(rg + j) * K_DIM + k0]);
            // 16 dot2 per matrix over this k-half; 4 independent chains
            float am0 = 0.f, am1 = 0.f, as0 = 0.f, as1 = 0.f;
            #pragma unroll
            for (int kk = 0; kk < 4; ++kk) {   // 4 x ds_read_b128 (2-addr bcast)
                half8v r = bp[kk];
                half2v q0 = __builtin_shufflevector(r, r, 0, 1);
                half2v q1 = __builtin_shufflevector(r, r, 2, 3);
                half2v q2 = __builtin_shufflevector(r, r, 4, 5);
                half2v q3 = __builtin_shufflevector(r, r, 6, 7);
                half8v wm = wmu_r[kk];
                half8v ws = wsig_r[kk];
                am0 = dot2h(q0, __builtin_shufflevector(wm, wm, 0, 1), am0);
                am1 = dot2h(q1, __builtin_shufflevector(wm, wm, 2, 3), am1);
                as0 = dot2h(q0, __builtin_shufflevector(ws, ws, 0, 1), as0);
                as1 = dot2h(q1, __builtin_shufflevector(ws, ws, 2, 3), as1);
                am0 = dot2h(q2, __builtin_shufflevector(wm, wm, 4, 5), am0);
                am1 = dot2h(q3, __builtin_shufflevector(wm, wm, 6, 7), am1);
                as0 = dot2h(q2, __builtin_shufflevector(ws, ws, 4, 5), as0);
                as1 = dot2h(q3, __builtin_shufflevector(ws, ws, 6, 7), as1);
            }
            float amv = am0 + am1;
            float asv = as0 + as1;
            amv += __shfl_xor(amv, 32, 64);    // combine k-halves
            asv += __shfl_xor(asv, 32, 64);
            const float mean = amv + bm;
            const float s    = asv + bs;
            if (cval) {
                if (lane < 32) {
                    out[o]      = fmaf(fabsf(s), e, mean);  // sample
                    out[o + BD] = mean;
                } else {
                    out[o + 2 * BD] = s * s;                // var
                }
            }
            o += D_DIM;
        }
    }
}

extern "C" void kernel_launch(void* const* d_in, const int* in_sizes, int n_in,
                              void* d_out, int out_size, void* d_ws, size_t ws_size,
                              hipStream_t stream) {
    const float* b    = (const float*)d_in[0];
    // d_in[1] = labels (unused by the reference outputs)
    const float* Wmu  = (const float*)d_in[2];
    const float* bmu  = (const float*)d_in[3];
    const float* Wsig = (const float*)d_in[4];
    const float* bsig = (const float*)d_in[5];
    const float* eps  = (const float*)d_in[6];
    float* out = (float*)d_out;
    __fp16* wp = (__fp16*)d_ws;               // 2*300*64*2 B = 76800 B

    hipLaunchKernelGGL(pack_wT_kernel, dim3(19), dim3(256), 0, stream,
                       Wmu, Wsig, wp);
    hipLaunchKernelGGL(sem_dec_kernel, dim3(B_ROWS / ROWS_PER_BLOCK),
                       dim3(THREADS), 0, stream,
                       b, bmu, bsig, eps, wp, out);
}

// Round 7
// 128.773 us; speedup vs baseline: 1.1250x; 1.1250x over previous
//
#include <hip/hip_runtime.h>
#include <hip/hip_bf16.h>

// SemanticDecoder: mean = b@Wmu+bmu; s = b@Wsig+bsig; var = s*s;
// sample = mean + |s|*eps.  B=65536, K=64, D=300. f32 in/out.
// Outputs concatenated: [sample, mean, var], each B*D.
//
// R7 = R6 (K-split, 640 thr) + THE FIX: weight dwords pinned in VGPRs via
// opaque asm ("+v") so the compiler cannot sink/rematerialize the
// loop-invariant weight loads into the row loop (VGPR_Count=36 in R6 proved
// it was reloading weights from L1 every row — the hidden ~90us stall).
// Plus 2-row interleave: 8 ds_read_b128 per lgkmcnt wait, 8 dot chains.

#define B_ROWS 65536
#define K_DIM 64
#define D_DIM 300
#define ROWS_PER_BLOCK 64
#define THREADS 640

typedef __fp16 half2v __attribute__((ext_vector_type(2)));
typedef __fp16 half4v __attribute__((ext_vector_type(4)));
typedef __fp16 half8v __attribute__((ext_vector_type(8)));

__device__ __forceinline__ float dot2h(half2v a, half2v b, float c) {
#if __has_builtin(__builtin_amdgcn_fdot2)
    return __builtin_amdgcn_fdot2(a, b, c, false);
#else
    return fmaf((float)a[0], (float)b[0], fmaf((float)a[1], (float)b[1], c));
#endif
}

__device__ __forceinline__ half2v h2(unsigned int u) {
    return __builtin_bit_cast(half2v, u);
}

// ---- kernel 1: W[64][300] f32 -> wp[m][d][k] f16 (transposed, packed) ----
__global__ void pack_wT_kernel(const float* __restrict__ Wmu,
                               const float* __restrict__ Wsig,
                               __fp16* __restrict__ wp)
{
    const int t = blockIdx.x * blockDim.x + threadIdx.x;
    if (t >= 2 * D_DIM * (K_DIM / 8)) return;   // 4800 units of 8 k-values
    const int g = t & 7;
    const int d = (t >> 3) % D_DIM;
    const int m = t / (D_DIM * 8);
    const float* W = m ? Wsig : Wmu;
    half8v o;
    #pragma unroll
    for (int e = 0; e < 8; ++e)
        o[e] = (__fp16)W[(size_t)(g * 8 + e) * D_DIM + d];
    *reinterpret_cast<half8v*>(&wp[((size_t)m * D_DIM + d) * K_DIM + g * 8]) = o;
}

// ---- main kernel ---------------------------------------------------------
__global__ __launch_bounds__(THREADS, 2) void sem_dec_kernel(
    const float* __restrict__ b,
    const float* __restrict__ bmu,
    const float* __restrict__ bsig,
    const float* __restrict__ eps,
    const __fp16* __restrict__ wp,
    float* __restrict__ out)
{
    __shared__ __fp16 lds_bh[ROWS_PER_BLOCK * K_DIM]; // 8 KB packed f16

    const int tid  = threadIdx.x;
    const int row0 = blockIdx.x * ROWS_PER_BLOCK;

    // ---- stage b[row0:row0+64, 0:64] -> LDS as f16 ----
    {
        const float4* gb = reinterpret_cast<const float4*>(b + (size_t)row0 * K_DIM);
        const int n4 = ROWS_PER_BLOCK * K_DIM / 4; // 1024
        for (int i = tid; i < n4; i += THREADS) {
            float4 v = gb[i];
            half2v p0 = __builtin_amdgcn_cvt_pkrtz(v.x, v.y);
            half2v p1 = __builtin_amdgcn_cvt_pkrtz(v.z, v.w);
            half4v p = __builtin_shufflevector(p0, p1, 0, 1, 2, 3);
            *reinterpret_cast<half4v*>(&lds_bh[4 * i]) = p;
        }
    }
    __syncthreads();

    const int lane  = tid & 63;
    const int wid   = tid >> 6;            // 0..9
    const int khalf = lane >> 5;           // 0: k 0..31, 1: k 32..63
    const int cr    = wid * 32 + (lane & 31);
    const bool cval = (cr < D_DIM);
    const int c     = cval ? cr : (D_DIM - 1);
    const int k0    = khalf * 32;

    // ---- k-half weight slice: 32 dwords, loaded once, PINNED in VGPRs ----
    unsigned int wmd[16], wsd[16];
    {
        const uint4* wm4 = reinterpret_cast<const uint4*>(
            wp + (size_t)c * K_DIM + k0);
        const uint4* ws4 = reinterpret_cast<const uint4*>(
            wp + ((size_t)D_DIM + c) * K_DIM + k0);
        #pragma unroll
        for (int j = 0; j < 4; ++j) {
            uint4 a = wm4[j];
            wmd[4*j+0] = a.x; wmd[4*j+1] = a.y; wmd[4*j+2] = a.z; wmd[4*j+3] = a.w;
            uint4 s = ws4[j];
            wsd[4*j+0] = s.x; wsd[4*j+1] = s.y; wsd[4*j+2] = s.z; wsd[4*j+3] = s.w;
        }
    }
    float bm = bmu[c];
    float bs = bsig[c];
    #pragma unroll
    for (int i = 0; i < 16; ++i) {
        asm volatile("" : "+v"(wmd[i]));   // opaque: cannot be rematerialized
        asm volatile("" : "+v"(wsd[i]));
    }
    asm volatile("" : "+v"(bm));
    asm volatile("" : "+v"(bs));

    const size_t BD = (size_t)B_ROWS * D_DIM;
    size_t o = (size_t)row0 * D_DIM + c;

    // eps pipeline: one 2-row group of lead
    float eA = eps[o];
    float eB = eps[o + D_DIM];

    for (int rg = 0; rg < ROWS_PER_BLOCK; rg += 2) {
        const float fA = eA, fB = eB;
        if (rg + 2 < ROWS_PER_BLOCK) {
            eA = eps[o + 2 * (size_t)D_DIM];
            eB = eps[o + 3 * (size_t)D_DIM];
        }
        // 8 ds_read_b128 issued together -> one lgkmcnt wait for 2 rows
        const uint4* bpA = reinterpret_cast<const uint4*>(
            &lds_bh[(rg + 0) * K_DIM + k0]);
        const uint4* bpB = reinterpret_cast<const uint4*>(
            &lds_bh[(rg + 1) * K_DIM + k0]);
        uint4 rA[4], rB[4];
        #pragma unroll
        for (int kk = 0; kk < 4; ++kk) { rA[kk] = bpA[kk]; rB[kk] = bpB[kk]; }

        // 8 independent dot chains: {rowA,rowB} x {mu,sig} x {even,odd dword}
        float amA0 = 0.f, amA1 = 0.f, asA0 = 0.f, asA1 = 0.f;
        float amB0 = 0.f, amB1 = 0.f, asB0 = 0.f, asB1 = 0.f;
        #pragma unroll
        for (int kk = 0; kk < 4; ++kk) {
            const half2v qA0 = h2(rA[kk].x), qA1 = h2(rA[kk].y);
            const half2v qA2 = h2(rA[kk].z), qA3 = h2(rA[kk].w);
            const half2v qB0 = h2(rB[kk].x), qB1 = h2(rB[kk].y);
            const half2v qB2 = h2(rB[kk].z), qB3 = h2(rB[kk].w);
            amA0 = dot2h(qA0, h2(wmd[4*kk+0]), amA0);
            amA1 = dot2h(qA1, h2(wmd[4*kk+1]), amA1);
            asA0 = dot2h(qA0, h2(wsd[4*kk+0]), asA0);
            asA1 = dot2h(qA1, h2(wsd[4*kk+1]), asA1);
            amB0 = dot2h(qB0, h2(wmd[4*kk+0]), amB0);
            amB1 = dot2h(qB1, h2(wmd[4*kk+1]), amB1);
            asB0 = dot2h(qB0, h2(wsd[4*kk+0]), asB0);
            asB1 = dot2h(qB1, h2(wsd[4*kk+1]), asB1);
            amA0 = dot2h(qA2, h2(wmd[4*kk+2]), amA0);
            amA1 = dot2h(qA3, h2(wmd[4*kk+3]), amA1);
            asA0 = dot2h(qA2, h2(wsd[4*kk+2]), asA0);
            asA1 = dot2h(qA3, h2(wsd[4*kk+3]), asA1);
            amB0 = dot2h(qB2, h2(wmd[4*kk+2]), amB0);
            amB1 = dot2h(qB3, h2(wmd[4*kk+3]), amB1);
            asB0 = dot2h(qB2, h2(wsd[4*kk+2]), asB0);
            asB1 = dot2h(qB3, h2(wsd[4*kk+3]), asB1);
        }
        float amA = amA0 + amA1, asA = asA0 + asA1;
        float amB = amB0 + amB1, asB = asB0 + asB1;
        amA += __shfl_xor(amA, 32, 64);    // combine k-halves
        asA += __shfl_xor(asA, 32, 64);
        amB += __shfl_xor(amB, 32, 64);
        asB += __shfl_xor(asB, 32, 64);

        if (cval) {
            const float meanA = amA + bm, sA = asA + bs;
            const float meanB = amB + bm, sB = asB + bs;
            if (lane < 32) {
                out[o]              = fmaf(fabsf(sA), fA, meanA);  // sample A
                out[o + BD]         = meanA;
                out[o + D_DIM]      = fmaf(fabsf(sB), fB, meanB);  // sample B
                out[o + D_DIM + BD] = meanB;
            } else {
                out[o + 2 * BD]         = sA * sA;                 // var A
                out[o + D_DIM + 2 * BD] = sB * sB;                 // var B
            }
        }
        o += 2 * (size_t)D_DIM;
    }
}

extern "C" void kernel_launch(void* const* d_in, const int* in_sizes, int n_in,
                              void* d_out, int out_size, void* d_ws, size_t ws_size,
                              hipStream_t stream) {
    const float* b    = (const float*)d_in[0];
    // d_in[1] = labels (unused by the reference outputs)
    const float* Wmu  = (const float*)d_in[2];
    const float* bmu  = (const float*)d_in[3];
    const float* Wsig = (const float*)d_in[4];
    const float* bsig = (const float*)d_in[5];
    const float* eps  = (const float*)d_in[6];
    float* out = (float*)d_out;
    __fp16* wp = (__fp16*)d_ws;               // 2*300*64*2 B = 76800 B

    hipLaunchKernelGGL(pack_wT_kernel, dim3(19), dim3(256), 0, stream,
                       Wmu, Wsig, wp);
    hipLaunchKernelGGL(sem_dec_kernel, dim3(B_ROWS / ROWS_PER_BLOCK),
                       dim3(THREADS), 0, stream,
                       b, bmu, bsig, eps, wp, out);
}